// Round 7
// baseline (3446.326 us; speedup 1.0000x reference)
//
#include <hip/hip_runtime.h>
#include <cstdint>
#include <cstddef>

#define NV 50000
#define NE 300
#define NH 256
#define NR 2048
#define NL0 128
#define NLR 64
#define NS 2049      // R + 1
#define G3 768       // 3*H

// ---------------- workspace layout ----------------
static constexpr size_t alignUp(size_t x, size_t a) { return (x + a - 1) / a * a; }
static constexpr size_t OFF_CTX    = 0;                              // 256 f32 (atomicAdd target)
static constexpr size_t OFF_SCORES = OFF_CTX + 1024;                 // 2049 f32
static constexpr size_t OFF_X      = alignUp(OFF_SCORES + (size_t)NS * 4, 256);
static constexpr size_t OFF_GI_F   = alignUp(OFF_X + (size_t)NS * NE * 4, 256);
static constexpr size_t OFF_GI_B   = alignUp(OFF_GI_F + (size_t)NS * G3 * 4, 256);
static constexpr size_t OFF_OUT2   = alignUp(OFF_GI_B + (size_t)NS * G3 * 4, 256);

typedef _Float16 half2t __attribute__((ext_vector_type(2)));

#if __has_builtin(__builtin_amdgcn_fdot2)
__device__ __forceinline__ float fdot2(half2t a, half2t b, float c) {
    return __builtin_amdgcn_fdot2(a, b, c, false);
}
#else
__device__ __forceinline__ float fdot2(half2t a, half2t b, float c) {
    return c + (float)a[0] * (float)b[0] + (float)a[1] * (float)b[1];
}
#endif

// tanh via 1 - 2/(e^{2x}+1): exact saturation at +/-1, no NaN for finite x,
// ~4 instructions vs the branchy library tanhf.
__device__ __forceinline__ float tanh_fast(float x) {
    float t = __expf(2.f * x);
    return 1.f - 2.f / (t + 1.f);
}

// ---------------- 1) X = [orig_sum ; reply_sums] ----------------
__global__ __launch_bounds__(320) void embed_sum_kernel(
    const int* __restrict__ otok, const int* __restrict__ rtok,
    const int* __restrict__ rlen, const float* __restrict__ embed,
    float* __restrict__ X)
{
    const int b = blockIdx.x;      // 0..2048
    const int e = threadIdx.x;     // < 300 active
    if (e >= NE) return;
    float acc = 0.f;
    if (b == 0) {
        for (int t = 0; t < NL0; ++t) {
            int tok = otok[t];
            acc += embed[(size_t)tok * NE + e];
        }
    } else {
        const int r = b - 1;
        const int L = rlen[r];
        const int* tr = rtok + (size_t)r * NLR;
        for (int t = 0; t < L; ++t) {
            int tok = tr[t];
            acc += embed[(size_t)tok * NE + e];
        }
    }
    X[(size_t)b * NE + e] = acc;
}

// ---------------- 2) C[M,N] = A[M,K] @ B[N,K]^T + bias[N] ----------------
__global__ __launch_bounds__(256) void gemm_abt(
    const float* __restrict__ A, const float* __restrict__ B,
    const float* __restrict__ bias, float* __restrict__ C,
    int M, int N, int K, int ldc)
{
    __shared__ float As[16][65];
    __shared__ float Bs[16][65];
    const int bm = blockIdx.x * 64, bn = blockIdx.y * 64;
    const int tid = threadIdx.x;
    const int tx = tid & 15, ty = tid >> 4;
    float acc[4][4] = {};
    for (int k0 = 0; k0 < K; k0 += 16) {
        #pragma unroll
        for (int i = 0; i < 4; ++i) {
            int l = tid + 256 * i;
            int mm = l >> 4, kk = l & 15;
            int gm = bm + mm, gk = k0 + kk;
            As[kk][mm] = (gm < M && gk < K) ? A[(size_t)gm * K + gk] : 0.f;
            int gn = bn + mm;
            Bs[kk][mm] = (gk < K) ? B[(size_t)gn * K + gk] : 0.f;
        }
        __syncthreads();
        #pragma unroll
        for (int kk = 0; kk < 16; ++kk) {
            float a0 = As[kk][ty], a1 = As[kk][ty+16], a2 = As[kk][ty+32], a3 = As[kk][ty+48];
            float b0 = Bs[kk][tx], b1 = Bs[kk][tx+16], b2 = Bs[kk][tx+32], b3 = Bs[kk][tx+48];
            acc[0][0] += a0*b0; acc[0][1] += a0*b1; acc[0][2] += a0*b2; acc[0][3] += a0*b3;
            acc[1][0] += a1*b0; acc[1][1] += a1*b1; acc[1][2] += a1*b2; acc[1][3] += a1*b3;
            acc[2][0] += a2*b0; acc[2][1] += a2*b1; acc[2][2] += a2*b2; acc[2][3] += a2*b3;
            acc[3][0] += a3*b0; acc[3][1] += a3*b1; acc[3][2] += a3*b2; acc[3][3] += a3*b3;
        }
        __syncthreads();
    }
    #pragma unroll
    for (int i = 0; i < 4; ++i) {
        int gm = bm + ty + 16 * i;
        if (gm >= M) continue;
        #pragma unroll
        for (int j = 0; j < 4; ++j) {
            int gn = bn + tx + 16 * j;
            C[(size_t)gm * ldc + gn] = acc[i][j] + bias[gn];
        }
    }
}

// ---------------- DPP quad-perm add: CTRL=0xB1 lane^1, CTRL=0x4E lane^2 ----------------
template<int CTRL>
__device__ __forceinline__ float dpp_add(float x) {
    int v = __builtin_amdgcn_update_dpp(0, __float_as_int(x), CTRL, 0xF, 0xF, true);
    return x + __int_as_float(v);
}

// ---------------- 3) bidirectional GRU recurrence: ZERO-COMMUNICATION ----------------
// 2 blocks x 1024 threads, one per direction; each direction entirely on ONE CU.
// Thread (e = tid>>2, q = tid&3): rows {e,256+e,512+e} over a 64-col quarter
// = 96 half2 weight VGPRs; v_dot2_f32_f16 accumulate; 2-DPP quad all-reduce.
//
// Register-allocation history (goal: weight array in ARCH VGPRs, zero moves):
//   r3 512thr:            VGPR=128 (AGPR-ized, 2500us)
//   r4 512thr lb(512,2):  VGPR=128 (2nd arg is only a MIN -- no effect)
//   r5 1024thr:           VGPR=64  (allocator chose 8 waves/EU, worse)
//   r6 512thr wpe(2,2):   VGPR=128 (total budget moved, arch split didn't)
// This round: 1024thr + waves_per_eu(4,4) -> budget exactly 128 regs/wave and the
// per-thread need (96 weights + ~25 working) FITS -> all-arch, no moves.
// Also: out2 store deferred one step (the __syncthreads vmcnt(0) drain was putting
// ~300-500cy of store-ack on EVERY step's critical path), fast tanh.
//   - LDS: f16 h-shadow quarters at 144 B stride -- SQ_LDS_BANK_CONFLICT==0 (r5).
//   - h carried in f32 (exact update math), f16 shadow only as the dot operand.
__global__ __launch_bounds__(1024)
__attribute__((amdgpu_waves_per_eu(4, 4)))
void gru_kernel(
    const float* __restrict__ Whh_f, const float* __restrict__ bhh_f,
    const float* __restrict__ Whh_b, const float* __restrict__ bhh_b,
    const float* __restrict__ gi_f, const float* __restrict__ gi_b,
    float* __restrict__ out2)
{
    const int dir = blockIdx.x;
    const int tid = threadIdx.x;
    const int e   = tid >> 2;      // 0..255  (h element)
    const int q   = tid & 3;       // column quarter [64q, 64q+64)

    const float* __restrict__ Whh = dir ? Whh_b : Whh_f;
    const float* __restrict__ bhh = dir ? bhh_b : bhh_f;
    const float* __restrict__ gi  = dir ? gi_b  : gi_f;

    // f16 shadow of h: [parity][quarter][64 + 8 pad]  (144 B quarter stride)
    __shared__ __align__(16) _Float16 hl16[2][4][72];
    __shared__ float hf32[2][NH];                     // f32 h (exact carry)

    if (tid < NH) {
        hl16[0][tid >> 6][tid & 63] = (_Float16)0.f;
        hf32[0][tid] = 0.f;
    }

    // ---- stage weights into 96 f16x2 VGPRs (one-time) ----
    half2t wr[32], wz[32], wn[32];
    {
        const float2* r0 = (const float2*)(Whh + (size_t)e * NH            + q * 64);
        const float2* r1 = (const float2*)(Whh + (size_t)(NH + e) * NH     + q * 64);
        const float2* r2 = (const float2*)(Whh + (size_t)(2 * NH + e) * NH + q * 64);
        #pragma unroll
        for (int c = 0; c < 32; ++c) {
            float2 a = r0[c], b = r1[c], d = r2[c];
            wr[c] = half2t{(_Float16)a.x, (_Float16)a.y};
            wz[c] = half2t{(_Float16)b.x, (_Float16)b.y};
            wn[c] = half2t{(_Float16)d.x, (_Float16)d.y};
        }
    }
    const float bhr = bhh[e], bhz = bhh[NH + e], bhn = bhh[2 * NH + e];

    // first step's gi
    float gir, giz, gin;
    {
        const float* g0 = gi + (size_t)(dir ? NS - 1 : 0) * G3 + e;
        gir = g0[0]; giz = g0[NH]; gin = g0[2 * NH];
    }
    // deferred out2 store state (q==0 threads)
    float  hnPend = 0.f;
    size_t offPend = 0;
    __syncthreads();

    for (int t = 0; t < NS; ++t) {
        const int p = t & 1;
        const int s = dir ? (NS - 1 - t) : t;

        // flush PREVIOUS step's out2 value: issued right after the barrier, it has
        // the whole step body to retire before the end-of-step vmcnt(0) drain.
        if (q == 0 && t > 0) out2[offPend] = hnPend;

        // prefetch next step's gi (completes under the dot stream)
        float girN = 0.f, gizN = 0.f, ginN = 0.f;
        if (t < NS - 1) {
            const float* gn = gi + (size_t)(dir ? (NS - 2 - t) : (t + 1)) * G3 + e;
            girN = gn[0]; gizN = gn[NH]; ginN = gn[2 * NH];
        }

        const float hprev = hf32[p][e];
        const uint4* hq = (const uint4*)(&hl16[p][q][0]);   // 8 x b128, conflict-free

        float ar = 0.f, az = 0.f, an = 0.f;
        #pragma unroll
        for (int c = 0; c < 8; ++c) {
            uint4 u = hq[c];
            half2t h0 = __builtin_bit_cast(half2t, u.x);
            half2t h1 = __builtin_bit_cast(half2t, u.y);
            half2t h2 = __builtin_bit_cast(half2t, u.z);
            half2t h3 = __builtin_bit_cast(half2t, u.w);
            ar = fdot2(wr[c*4+0], h0, ar); az = fdot2(wz[c*4+0], h0, az); an = fdot2(wn[c*4+0], h0, an);
            ar = fdot2(wr[c*4+1], h1, ar); az = fdot2(wz[c*4+1], h1, az); an = fdot2(wn[c*4+1], h1, an);
            ar = fdot2(wr[c*4+2], h2, ar); az = fdot2(wz[c*4+2], h2, az); an = fdot2(wn[c*4+2], h2, an);
            ar = fdot2(wr[c*4+3], h3, ar); az = fdot2(wz[c*4+3], h3, az); an = fdot2(wn[c*4+3], h3, an);
        }
        // quad all-reduce across the 4 column-quarters (lane^1 then lane^2)
        ar = dpp_add<0xB1>(ar); az = dpp_add<0xB1>(az); an = dpp_add<0xB1>(an);
        ar = dpp_add<0x4E>(ar); az = dpp_add<0x4E>(az); an = dpp_add<0x4E>(an);

        const float r  = 1.f / (1.f + __expf(-(gir + ar + bhr)));
        const float z  = 1.f / (1.f + __expf(-(giz + az + bhz)));
        const float n  = tanh_fast(gin + r * (an + bhn));
        const float hn = (1.f - z) * n + z * hprev;

        if (q == 0) {
            hf32[p ^ 1][e] = hn;
            hl16[p ^ 1][e >> 6][e & 63] = (_Float16)hn;
            hnPend  = hn;
            offPend = (size_t)s * (2 * NH) + dir * NH + e;
        }
        gir = girN; giz = gizN; gin = ginN;
        __syncthreads();
    }
    if (q == 0) out2[offPend] = hnPend;   // flush last step
}

// ---------------- 4) scores[s] = dot(output[s], h_f + h_b) ----------------
__global__ __launch_bounds__(256) void scores_kernel(
    const float* __restrict__ outp, const float* __restrict__ out2,
    float* __restrict__ scores)
{
    const int s = blockIdx.x, m = threadIdx.x;
    float hs = out2[(size_t)(NS - 1) * (2 * NH) + m] + out2[NH + m];
    float v = outp[(size_t)s * NH + m] * hs;
    #pragma unroll
    for (int o = 32; o > 0; o >>= 1) v += __shfl_down(v, o);
    __shared__ float p[4];
    if ((m & 63) == 0) p[m >> 6] = v;
    __syncthreads();
    if (m == 0) scores[s] = p[0] + p[1] + p[2] + p[3];
}

// ---------------- 5) softmax over 2049 scores (in place) ----------------
__global__ __launch_bounds__(1024) void softmax_kernel(float* __restrict__ sc)
{
    const int tid = threadIdx.x;
    __shared__ float red[16];
    float x0 = (tid < NS) ? sc[tid] : -3.0e38f;
    float x1 = (tid + 1024 < NS) ? sc[tid + 1024] : -3.0e38f;
    float mx = fmaxf(x0, x1);
    #pragma unroll
    for (int o = 32; o > 0; o >>= 1) mx = fmaxf(mx, __shfl_xor(mx, o));
    if ((tid & 63) == 0) red[tid >> 6] = mx;
    __syncthreads();
    if (tid == 0) {
        float m = red[0];
        for (int i = 1; i < 16; ++i) m = fmaxf(m, red[i]);
        red[0] = m;
    }
    __syncthreads();
    const float gmax = red[0];
    float e0 = (tid < NS) ? __expf(x0 - gmax) : 0.f;
    float e1 = (tid + 1024 < NS) ? __expf(x1 - gmax) : 0.f;
    float sm = e0 + e1;
    #pragma unroll
    for (int o = 32; o > 0; o >>= 1) sm += __shfl_xor(sm, o);
    __syncthreads();
    if ((tid & 63) == 0) red[tid >> 6] = sm;
    __syncthreads();
    if (tid == 0) {
        float su = 0.f;
        for (int i = 0; i < 16; ++i) su += red[i];
        red[1] = 1.f / su;
    }
    __syncthreads();
    const float inv = red[1];
    if (tid < NS) sc[tid] = e0 * inv;
    if (tid + 1024 < NS) sc[tid + 1024] = e1 * inv;
}

// ---------------- 6) ctx[m] += sum_s w[s]*output[s][m] (partial per block) ----------------
__global__ __launch_bounds__(256) void ctx_kernel(
    const float* __restrict__ outp, const float* __restrict__ w,
    float* __restrict__ ctx)
{
    const int m = threadIdx.x;
    const int s0 = blockIdx.x * 128;
    const int s1 = min(s0 + 128, NS);
    float acc = 0.f;
    for (int s = s0; s < s1; ++s) acc += w[s] * outp[(size_t)s * NH + m];
    atomicAdd(&ctx[m], acc);
}

// ---------------- 7) result + loss ----------------
__global__ __launch_bounds__(256) void final_kernel(
    const float* __restrict__ ctx, const float* __restrict__ Wo,
    const float* __restrict__ bo, const float* __restrict__ label,
    float* __restrict__ dout)
{
    const int m = threadIdx.x;
    float v = ctx[m] * Wo[m];
    #pragma unroll
    for (int o = 32; o > 0; o >>= 1) v += __shfl_down(v, o);
    __shared__ float p[4];
    if ((m & 63) == 0) p[m >> 6] = v;
    __syncthreads();
    if (m == 0) {
        float x = p[0] + p[1] + p[2] + p[3] + bo[0];
        float result = 1.f / (1.f + __expf(-x));
        float d = label[0] - result;
        dout[(size_t)NS * NH]     = d * d;
        dout[(size_t)NS * NH + 1] = result;
    }
}

extern "C" void kernel_launch(void* const* d_in, const int* in_sizes, int n_in,
                              void* d_out, int out_size, void* d_ws, size_t ws_size,
                              hipStream_t stream)
{
    const int*   otok  = (const int*)d_in[0];
    const int*   rtok  = (const int*)d_in[1];
    const int*   rlen  = (const int*)d_in[2];
    const float* label = (const float*)d_in[3];
    const float* embed = (const float*)d_in[4];
    const float* Wih_f = (const float*)d_in[5];
    const float* Whh_f = (const float*)d_in[6];
    const float* bih_f = (const float*)d_in[7];
    const float* bhh_f = (const float*)d_in[8];
    const float* Wih_b = (const float*)d_in[9];
    const float* Whh_b = (const float*)d_in[10];
    const float* bih_b = (const float*)d_in[11];
    const float* bhh_b = (const float*)d_in[12];
    const float* Wl    = (const float*)d_in[13];
    const float* bl    = (const float*)d_in[14];
    const float* Wo    = (const float*)d_in[15];
    const float* bo    = (const float*)d_in[16];

    char* ws = (char*)d_ws;
    float* ctx    = (float*)(ws + OFF_CTX);
    float* scores = (float*)(ws + OFF_SCORES);
    float* X      = (float*)(ws + OFF_X);
    float* gi_f   = (float*)(ws + OFF_GI_F);
    float* gi_b   = (float*)(ws + OFF_GI_B);
    float* out2   = (float*)(ws + OFF_OUT2);
    float* outp   = (float*)d_out;   // first 2049*256 floats = `output`

    // zero ctx accumulator (graph-capture-safe)
    hipMemsetAsync(ws + OFF_CTX, 0, 1024, stream);

    // 1) embedding sums
    embed_sum_kernel<<<NS, 320, 0, stream>>>(otok, rtok, rlen, embed, X);

    // 2) input-gate pre-GEMMs: gi = X @ Wih^T + bih  (both directions)
    gemm_abt<<<dim3(33, 12), 256, 0, stream>>>(X, Wih_f, bih_f, gi_f, NS, G3, NE, G3);
    gemm_abt<<<dim3(33, 12), 256, 0, stream>>>(X, Wih_b, bih_b, gi_b, NS, G3, NE, G3);

    // 3) recurrence: one self-contained CU per direction (no inter-WG traffic)
    gru_kernel<<<2, 1024, 0, stream>>>(Whh_f, bhh_f, Whh_b, bhh_b,
                                       gi_f, gi_b, out2);

    // 4) output = out2 @ Wl^T + bl  -> d_out
    gemm_abt<<<dim3(33, 4), 256, 0, stream>>>(out2, Wl, bl, outp, NS, NH, 2 * NH, NH);

    // 5) attention + head
    scores_kernel<<<NS, 256, 0, stream>>>(outp, out2, scores);
    softmax_kernel<<<1, 1024, 0, stream>>>(scores);
    ctx_kernel<<<(NS + 127) / 128, 256, 0, stream>>>(outp, scores, ctx);
    final_kernel<<<1, 256, 0, stream>>>(ctx, Wo, bo, label, (float*)d_out);
}

// Round 8
// 2756.782 us; speedup vs baseline: 1.2501x; 1.2501x over previous
//
#include <hip/hip_runtime.h>
#include <cstdint>
#include <cstddef>

#define NV 50000
#define NE 300
#define NH 256
#define NR 2048
#define NL0 128
#define NLR 64
#define NS 2049      // R + 1
#define G3 768       // 3*H

// ---------------- workspace layout ----------------
static constexpr size_t alignUp(size_t x, size_t a) { return (x + a - 1) / a * a; }
static constexpr size_t OFF_CTX    = 0;                              // 256 f32 (atomicAdd target)
static constexpr size_t OFF_SCORES = OFF_CTX + 1024;                 // 2049 f32
static constexpr size_t OFF_X      = alignUp(OFF_SCORES + (size_t)NS * 4, 256);
static constexpr size_t OFF_GI_F   = alignUp(OFF_X + (size_t)NS * NE * 4, 256);
static constexpr size_t OFF_GI_B   = alignUp(OFF_GI_F + (size_t)NS * G3 * 4, 256);
static constexpr size_t OFF_OUT2   = alignUp(OFF_GI_B + (size_t)NS * G3 * 4, 256);

typedef _Float16 half2t __attribute__((ext_vector_type(2)));

#if __has_builtin(__builtin_amdgcn_fdot2)
__device__ __forceinline__ float fdot2(half2t a, half2t b, float c) {
    return __builtin_amdgcn_fdot2(a, b, c, false);
}
#else
__device__ __forceinline__ float fdot2(half2t a, half2t b, float c) {
    return c + (float)a[0] * (float)b[0] + (float)a[1] * (float)b[1];
}
#endif

// tanh via 1 - 2/(e^{2x}+1): exact saturation at +/-1, no NaN for finite x.
__device__ __forceinline__ float tanh_fast(float x) {
    float t = __expf(2.f * x);
    return 1.f - 2.f / (t + 1.f);
}

// ---------------- 1) X = [orig_sum ; reply_sums] ----------------
__global__ __launch_bounds__(320) void embed_sum_kernel(
    const int* __restrict__ otok, const int* __restrict__ rtok,
    const int* __restrict__ rlen, const float* __restrict__ embed,
    float* __restrict__ X)
{
    const int b = blockIdx.x;      // 0..2048
    const int e = threadIdx.x;     // < 300 active
    if (e >= NE) return;
    float acc = 0.f;
    if (b == 0) {
        for (int t = 0; t < NL0; ++t) {
            int tok = otok[t];
            acc += embed[(size_t)tok * NE + e];
        }
    } else {
        const int r = b - 1;
        const int L = rlen[r];
        const int* tr = rtok + (size_t)r * NLR;
        for (int t = 0; t < L; ++t) {
            int tok = tr[t];
            acc += embed[(size_t)tok * NE + e];
        }
    }
    X[(size_t)b * NE + e] = acc;
}

// ---------------- 2) C[M,N] = A[M,K] @ B[N,K]^T + bias[N] ----------------
__global__ __launch_bounds__(256) void gemm_abt(
    const float* __restrict__ A, const float* __restrict__ B,
    const float* __restrict__ bias, float* __restrict__ C,
    int M, int N, int K, int ldc)
{
    __shared__ float As[16][65];
    __shared__ float Bs[16][65];
    const int bm = blockIdx.x * 64, bn = blockIdx.y * 64;
    const int tid = threadIdx.x;
    const int tx = tid & 15, ty = tid >> 4;
    float acc[4][4] = {};
    for (int k0 = 0; k0 < K; k0 += 16) {
        #pragma unroll
        for (int i = 0; i < 4; ++i) {
            int l = tid + 256 * i;
            int mm = l >> 4, kk = l & 15;
            int gm = bm + mm, gk = k0 + kk;
            As[kk][mm] = (gm < M && gk < K) ? A[(size_t)gm * K + gk] : 0.f;
            int gn = bn + mm;
            Bs[kk][mm] = (gk < K) ? B[(size_t)gn * K + gk] : 0.f;
        }
        __syncthreads();
        #pragma unroll
        for (int kk = 0; kk < 16; ++kk) {
            float a0 = As[kk][ty], a1 = As[kk][ty+16], a2 = As[kk][ty+32], a3 = As[kk][ty+48];
            float b0 = Bs[kk][tx], b1 = Bs[kk][tx+16], b2 = Bs[kk][tx+32], b3 = Bs[kk][tx+48];
            acc[0][0] += a0*b0; acc[0][1] += a0*b1; acc[0][2] += a0*b2; acc[0][3] += a0*b3;
            acc[1][0] += a1*b0; acc[1][1] += a1*b1; acc[1][2] += a1*b2; acc[1][3] += a1*b3;
            acc[2][0] += a2*b0; acc[2][1] += a2*b1; acc[2][2] += a2*b2; acc[2][3] += a2*b3;
            acc[3][0] += a3*b0; acc[3][1] += a3*b1; acc[3][2] += a3*b2; acc[3][3] += a3*b3;
        }
        __syncthreads();
    }
    #pragma unroll
    for (int i = 0; i < 4; ++i) {
        int gm = bm + ty + 16 * i;
        if (gm >= M) continue;
        #pragma unroll
        for (int j = 0; j < 4; ++j) {
            int gn = bn + tx + 16 * j;
            C[(size_t)gm * ldc + gn] = acc[i][j] + bias[gn];
        }
    }
}

// ---------------- DPP pairwise add: lane += lane^1 (quad_perm [1,0,3,2]) ----------------
__device__ __forceinline__ float dpp_add_xor1(float x) {
    int v = __builtin_amdgcn_update_dpp(0, __float_as_int(x), 0xB1, 0xF, 0xF, true);
    return x + __int_as_float(v);
}

// ---------------- 3) bidirectional GRU recurrence: ZERO-COMMUNICATION ----------------
// 2 blocks x 512 threads, one per direction; each direction entirely on ONE CU.
// Thread (e = tid>>1, hsel = tid&1): rows {e, 256+e, 512+e} over cols
// [hsel*128, hsel*128+128) as 192 packed f16x2 VGPRs; v_dot2_f32_f16 accumulate.
//
// Register story (5 rounds of evidence): arch-VGPR count never responded to
// launch_bounds / waves_per_eu; it responds to PRESSURE PEAKS. The staging
// prologue (3 rows x 64 float2, fully unrolled) let the scheduler hoist ~384
// transient load regs -> allocator AGPR-ized the long-lived weight arrays ->
// every v_dot2 paid a v_accvgpr_read (dots can't read AGPRs) ~= +768 cy/step.
// Fix: chunk the staging 2-wide with sched_barrier(0) walls so the transient
// set stays ~12 regs; steady-state peak = 192 weights + ~40 working <= 256
// arch cap at 2 waves/EU -> weights stay architectural.
//   - out2 store DEFERRED one step: previous step's value is stored right
//     after the barrier, so the end-of-step vmcnt(0) drain never waits on a
//     fresh store-ack.
//   - LDS: f16 h-shadow halves at 320 B stride -- SQ_LDS_BANK_CONFLICT==0
//     verified (r4/r5/r6).
//   - h carried in f32 (exact update math), f16 shadow only as dot operand.
__global__ __launch_bounds__(512)
__attribute__((amdgpu_waves_per_eu(2, 2)))
void gru_kernel(
    const float* __restrict__ Whh_f, const float* __restrict__ bhh_f,
    const float* __restrict__ Whh_b, const float* __restrict__ bhh_b,
    const float* __restrict__ gi_f, const float* __restrict__ gi_b,
    float* __restrict__ out2)
{
    const int dir  = blockIdx.x;
    const int tid  = threadIdx.x;
    const int e    = tid >> 1;
    const int hsel = tid & 1;

    const float* __restrict__ Whh = dir ? Whh_b : Whh_f;
    const float* __restrict__ bhh = dir ? bhh_b : bhh_f;
    const float* __restrict__ gi  = dir ? gi_b  : gi_f;

    // f16 shadow of h: [parity][half][128 + 32 pad]  (pad => 320B half-stride)
    __shared__ __align__(16) _Float16 hl16[2][2][160];
    __shared__ float hf32[2][NH];                     // f32 h (exact carry)

    if (tid < NH) {
        hl16[0][tid >> 7][tid & 127] = (_Float16)0.f;
        hf32[0][tid] = 0.f;
    }

    // ---- stage weights into 192 f16x2 VGPRs ----
    // Chunked (2 cols) + sched_barrier walls: transient live set ~12 regs, so
    // the register-pressure PEAK never exceeds the arch budget (see header).
    half2t wr[64], wz[64], wn[64];
    {
        const float2* r0 = (const float2*)(Whh + (size_t)e * NH            + hsel * 128);
        const float2* r1 = (const float2*)(Whh + (size_t)(NH + e) * NH     + hsel * 128);
        const float2* r2 = (const float2*)(Whh + (size_t)(2 * NH + e) * NH + hsel * 128);
        #pragma unroll
        for (int c0 = 0; c0 < 64; c0 += 2) {
            #pragma unroll
            for (int c = c0; c < c0 + 2; ++c) {
                float2 a = r0[c], b = r1[c], d = r2[c];
                wr[c] = half2t{(_Float16)a.x, (_Float16)a.y};
                wz[c] = half2t{(_Float16)b.x, (_Float16)b.y};
                wn[c] = half2t{(_Float16)d.x, (_Float16)d.y};
            }
            __builtin_amdgcn_sched_barrier(0);   // no load-hoisting across chunks
        }
    }
    const float bhr = bhh[e], bhz = bhh[NH + e], bhn = bhh[2 * NH + e];

    // first step's gi
    float gir, giz, gin;
    {
        const float* g0 = gi + (size_t)(dir ? NS - 1 : 0) * G3 + e;
        gir = g0[0]; giz = g0[NH]; gin = g0[2 * NH];
    }
    // deferred out2 store state (hsel==0 threads); 32-bit index to save regs
    float hnPend = 0.f;
    int   offPend = 0;
    __syncthreads();

    for (int t = 0; t < NS; ++t) {
        const int p = t & 1;
        const int s = dir ? (NS - 1 - t) : t;

        // flush PREVIOUS step's out2 value: it now has the whole step body to
        // retire before this step's end-of-step vmcnt(0) barrier drain.
        if (hsel == 0 && t > 0) out2[offPend] = hnPend;

        // prefetch next step's gi (completes under the dot stream)
        float girN = 0.f, gizN = 0.f, ginN = 0.f;
        if (t < NS - 1) {
            const float* gn = gi + (size_t)(dir ? (NS - 2 - t) : (t + 1)) * G3 + e;
            girN = gn[0]; gizN = gn[NH]; ginN = gn[2 * NH];
        }

        const float hprev = hf32[p][e];
        const uint4* hq = (const uint4*)(&hl16[p][hsel][0]);   // 16 x b128, conflict-free

        // 6 accumulator chains (2 per gate) for ILP at 2 waves/SIMD
        float ar0 = 0.f, ar1 = 0.f, az0 = 0.f, az1 = 0.f, an0 = 0.f, an1 = 0.f;
        #pragma unroll
        for (int c = 0; c < 16; ++c) {
            uint4 u = hq[c];
            half2t h0 = __builtin_bit_cast(half2t, u.x);
            half2t h1 = __builtin_bit_cast(half2t, u.y);
            half2t h2 = __builtin_bit_cast(half2t, u.z);
            half2t h3 = __builtin_bit_cast(half2t, u.w);
            ar0 = fdot2(wr[c*4+0], h0, ar0); az0 = fdot2(wz[c*4+0], h0, az0); an0 = fdot2(wn[c*4+0], h0, an0);
            ar1 = fdot2(wr[c*4+1], h1, ar1); az1 = fdot2(wz[c*4+1], h1, az1); an1 = fdot2(wn[c*4+1], h1, an1);
            ar0 = fdot2(wr[c*4+2], h2, ar0); az0 = fdot2(wz[c*4+2], h2, az0); an0 = fdot2(wn[c*4+2], h2, an0);
            ar1 = fdot2(wr[c*4+3], h3, ar1); az1 = fdot2(wz[c*4+3], h3, az1); an1 = fdot2(wn[c*4+3], h3, an1);
        }
        float ar = ar0 + ar1, az = az0 + az1, an = an0 + an1;
        // combine the two column-halves: lane += lane^1 (both lanes get the sum)
        ar = dpp_add_xor1(ar);
        az = dpp_add_xor1(az);
        an = dpp_add_xor1(an);

        const float r  = 1.f / (1.f + __expf(-(gir + ar + bhr)));
        const float z  = 1.f / (1.f + __expf(-(giz + az + bhz)));
        const float n  = tanh_fast(gin + r * (an + bhn));
        const float hn = (1.f - z) * n + z * hprev;

        if (hsel == 0) {
            hf32[p ^ 1][e] = hn;
            hl16[p ^ 1][e >> 7][e & 127] = (_Float16)hn;
            hnPend  = hn;
            offPend = s * (2 * NH) + dir * NH + e;
        }
        gir = girN; giz = gizN; gin = ginN;
        __syncthreads();
    }
    if (hsel == 0) out2[offPend] = hnPend;   // flush last step
}

// ---------------- 4) scores[s] = dot(output[s], h_f + h_b) ----------------
__global__ __launch_bounds__(256) void scores_kernel(
    const float* __restrict__ outp, const float* __restrict__ out2,
    float* __restrict__ scores)
{
    const int s = blockIdx.x, m = threadIdx.x;
    float hs = out2[(size_t)(NS - 1) * (2 * NH) + m] + out2[NH + m];
    float v = outp[(size_t)s * NH + m] * hs;
    #pragma unroll
    for (int o = 32; o > 0; o >>= 1) v += __shfl_down(v, o);
    __shared__ float p[4];
    if ((m & 63) == 0) p[m >> 6] = v;
    __syncthreads();
    if (m == 0) scores[s] = p[0] + p[1] + p[2] + p[3];
}

// ---------------- 5) softmax over 2049 scores (in place) ----------------
__global__ __launch_bounds__(1024) void softmax_kernel(float* __restrict__ sc)
{
    const int tid = threadIdx.x;
    __shared__ float red[16];
    float x0 = (tid < NS) ? sc[tid] : -3.0e38f;
    float x1 = (tid + 1024 < NS) ? sc[tid + 1024] : -3.0e38f;
    float mx = fmaxf(x0, x1);
    #pragma unroll
    for (int o = 32; o > 0; o >>= 1) mx = fmaxf(mx, __shfl_xor(mx, o));
    if ((tid & 63) == 0) red[tid >> 6] = mx;
    __syncthreads();
    if (tid == 0) {
        float m = red[0];
        for (int i = 1; i < 16; ++i) m = fmaxf(m, red[i]);
        red[0] = m;
    }
    __syncthreads();
    const float gmax = red[0];
    float e0 = (tid < NS) ? __expf(x0 - gmax) : 0.f;
    float e1 = (tid + 1024 < NS) ? __expf(x1 - gmax) : 0.f;
    float sm = e0 + e1;
    #pragma unroll
    for (int o = 32; o > 0; o >>= 1) sm += __shfl_xor(sm, o);
    __syncthreads();
    if ((tid & 63) == 0) red[tid >> 6] = sm;
    __syncthreads();
    if (tid == 0) {
        float su = 0.f;
        for (int i = 0; i < 16; ++i) su += red[i];
        red[1] = 1.f / su;
    }
    __syncthreads();
    const float inv = red[1];
    if (tid < NS) sc[tid] = e0 * inv;
    if (tid + 1024 < NS) sc[tid + 1024] = e1 * inv;
}

// ---------------- 6) ctx[m] += sum_s w[s]*output[s][m] (partial per block) ----------------
__global__ __launch_bounds__(256) void ctx_kernel(
    const float* __restrict__ outp, const float* __restrict__ w,
    float* __restrict__ ctx)
{
    const int m = threadIdx.x;
    const int s0 = blockIdx.x * 128;
    const int s1 = min(s0 + 128, NS);
    float acc = 0.f;
    for (int s = s0; s < s1; ++s) acc += w[s] * outp[(size_t)s * NH + m];
    atomicAdd(&ctx[m], acc);
}

// ---------------- 7) result + loss ----------------
__global__ __launch_bounds__(256) void final_kernel(
    const float* __restrict__ ctx, const float* __restrict__ Wo,
    const float* __restrict__ bo, const float* __restrict__ label,
    float* __restrict__ dout)
{
    const int m = threadIdx.x;
    float v = ctx[m] * Wo[m];
    #pragma unroll
    for (int o = 32; o > 0; o >>= 1) v += __shfl_down(v, o);
    __shared__ float p[4];
    if ((m & 63) == 0) p[m >> 6] = v;
    __syncthreads();
    if (m == 0) {
        float x = p[0] + p[1] + p[2] + p[3] + bo[0];
        float result = 1.f / (1.f + __expf(-x));
        float d = label[0] - result;
        dout[(size_t)NS * NH]     = d * d;
        dout[(size_t)NS * NH + 1] = result;
    }
}

extern "C" void kernel_launch(void* const* d_in, const int* in_sizes, int n_in,
                              void* d_out, int out_size, void* d_ws, size_t ws_size,
                              hipStream_t stream)
{
    const int*   otok  = (const int*)d_in[0];
    const int*   rtok  = (const int*)d_in[1];
    const int*   rlen  = (const int*)d_in[2];
    const float* label = (const float*)d_in[3];
    const float* embed = (const float*)d_in[4];
    const float* Wih_f = (const float*)d_in[5];
    const float* Whh_f = (const float*)d_in[6];
    const float* bih_f = (const float*)d_in[7];
    const float* bhh_f = (const float*)d_in[8];
    const float* Wih_b = (const float*)d_in[9];
    const float* Whh_b = (const float*)d_in[10];
    const float* bih_b = (const float*)d_in[11];
    const float* bhh_b = (const float*)d_in[12];
    const float* Wl    = (const float*)d_in[13];
    const float* bl    = (const float*)d_in[14];
    const float* Wo    = (const float*)d_in[15];
    const float* bo    = (const float*)d_in[16];

    char* ws = (char*)d_ws;
    float* ctx    = (float*)(ws + OFF_CTX);
    float* scores = (float*)(ws + OFF_SCORES);
    float* X      = (float*)(ws + OFF_X);
    float* gi_f   = (float*)(ws + OFF_GI_F);
    float* gi_b   = (float*)(ws + OFF_GI_B);
    float* out2   = (float*)(ws + OFF_OUT2);
    float* outp   = (float*)d_out;   // first 2049*256 floats = `output`

    // zero ctx accumulator (graph-capture-safe)
    hipMemsetAsync(ws + OFF_CTX, 0, 1024, stream);

    // 1) embedding sums
    embed_sum_kernel<<<NS, 320, 0, stream>>>(otok, rtok, rlen, embed, X);

    // 2) input-gate pre-GEMMs: gi = X @ Wih^T + bih  (both directions)
    gemm_abt<<<dim3(33, 12), 256, 0, stream>>>(X, Wih_f, bih_f, gi_f, NS, G3, NE, G3);
    gemm_abt<<<dim3(33, 12), 256, 0, stream>>>(X, Wih_b, bih_b, gi_b, NS, G3, NE, G3);

    // 3) recurrence: one self-contained CU per direction (no inter-WG traffic)
    gru_kernel<<<2, 512, 0, stream>>>(Whh_f, bhh_f, Whh_b, bhh_b,
                                      gi_f, gi_b, out2);

    // 4) output = out2 @ Wl^T + bl  -> d_out
    gemm_abt<<<dim3(33, 4), 256, 0, stream>>>(out2, Wl, bl, outp, NS, NH, 2 * NH, NH);

    // 5) attention + head
    scores_kernel<<<NS, 256, 0, stream>>>(outp, out2, scores);
    softmax_kernel<<<1, 1024, 0, stream>>>(scores);
    ctx_kernel<<<(NS + 127) / 128, 256, 0, stream>>>(outp, scores, ctx);
    final_kernel<<<1, 256, 0, stream>>>(ctx, Wo, bo, label, (float*)d_out);
}